// Round 13
// baseline (591.001 us; speedup 1.0000x reference)
//
#include <hip/hip_runtime.h>
#include <math.h>

#define N_NODES 100000
#define N_EDGES 1600000
#define NBINS 391        // coarse bins: dst >> 8 (391*256 = 100096 >= 100000)
#define NCHUNK 400       // edge chunks
#define CHUNK 4000       // edges per chunk (400*4000 = 1.6M exact)
#define M_H (NBINS * NCHUNK)   // 156,400 histogram entries

typedef __attribute__((ext_vector_type(8))) short bf16x8;   // MFMA A/B frag (8 bf16)
typedef __attribute__((ext_vector_type(4))) float f32x4;    // MFMA C/D frag
typedef __attribute__((ext_vector_type(2))) float f32x2;    // packed pair -> v_pk_fma_f32

__device__ __forceinline__ unsigned short f2bf(float f) {   // RNE fp32->bf16
    unsigned int u = __float_as_uint(f);
    u += 0x7FFF + ((u >> 16) & 1);
    return (unsigned short)(u >> 16);
}
__device__ __forceinline__ float bf_lo(unsigned int u) { return __uint_as_float(u << 16); }
__device__ __forceinline__ float bf_hi(unsigned int u) { return __uint_as_float(u & 0xFFFF0000u); }
__device__ __forceinline__ f32x2 bfpair(unsigned int u) {
    f32x2 r; r.x = bf_lo(u); r.y = bf_hi(u); return r;
}

// ---------------- CSR build: two-level counting sort, LDS atomics only ----------------

// Pass A: per-chunk LDS histogram over coarse bins -> H[bin][chunk] (plain stores).
__global__ __launch_bounds__(256) void passA_kernel(const int* __restrict__ dst,
                                                    int* __restrict__ H) {
    __shared__ int lh[NBINS];
    int tid = threadIdx.x, c = blockIdx.x;
    for (int i = tid; i < NBINS; i += 256) lh[i] = 0;
    __syncthreads();
    int base = c * CHUNK;
    #pragma unroll
    for (int i = 0; i < 16; ++i) {
        int o = i * 256 + tid;
        if (o < CHUNK) atomicAdd(&lh[dst[base + o] >> 8], 1);   // LDS atomic
    }
    __syncthreads();
    for (int i = tid; i < NBINS; i += 256) H[i * NCHUNK + c] = lh[i];
}

// Pass B: exclusive scan of H (156,400 entries) in place. Single block of 1024.
__global__ __launch_bounds__(1024) void passB_kernel(int* __restrict__ H) {
    __shared__ int s[1024];
    int t = threadIdx.x;
    const int CH = (M_H + 1023) / 1024;   // 153
    int base = t * CH;
    int sum = 0;
    for (int i = 0; i < CH; ++i) {
        int idx = base + i;
        if (idx < M_H) sum += H[idx];
    }
    s[t] = sum;
    __syncthreads();
    for (int off = 1; off < 1024; off <<= 1) {
        int u = (t >= off) ? s[t - off] : 0;
        __syncthreads();
        s[t] += u;
        __syncthreads();
    }
    int run = s[t] - sum;                 // exclusive prefix of this thread's chunk
    for (int i = 0; i < CH; ++i) {
        int idx = base + i;
        if (idx < M_H) { int v = H[idx]; H[idx] = run; run += v; }
    }
}

// Pass C (merged): coarse scatter (blocks 0..399, LDS returning ranks -> rec) +
// x->bf16 convert (400..12899) + W1T/W2T converts (12900..12971).
// rec[pos] = src | (dst&255)<<17  (25 bits).
__global__ __launch_bounds__(256) void passC_kernel(const int* __restrict__ src,
                                                    const int* __restrict__ dst,
                                                    const int* __restrict__ H,
                                                    int* __restrict__ rec,
                                                    const float* __restrict__ x,
                                                    const float* __restrict__ W1,
                                                    const float* __restrict__ W2,
                                                    ushort* __restrict__ xb,
                                                    ushort* __restrict__ W1T,
                                                    ushort* __restrict__ W2T) {
    int b = blockIdx.x;
    if (b < NCHUNK) {
        __shared__ int base[NBINS];
        __shared__ int rk[NBINS];
        int tid = threadIdx.x;
        for (int i = tid; i < NBINS; i += 256) { base[i] = H[i * NCHUNK + b]; rk[i] = 0; }
        __syncthreads();
        int estart = b * CHUNK;
        #pragma unroll
        for (int i = 0; i < 16; ++i) {
            int o = i * 256 + tid;
            if (o < CHUNK) {
                int e = estart + o;
                int d = dst[e];
                int bin = d >> 8;
                int r = atomicAdd(&rk[bin], 1);          // LDS returning atomic (fast)
                rec[base[bin] + r] = src[e] | ((d & 255) << 17);
            }
        }
    } else if (b < NCHUNK + 12500) {                     // x -> bf16 (node-major)
        int i = (b - NCHUNK) * 256 + threadIdx.x;
        float4 v = *(const float4*)&x[i * 4];
        ushort4 o;
        o.x = f2bf(v.x); o.y = f2bf(v.y); o.z = f2bf(v.z); o.w = f2bf(v.w);
        *(ushort4*)&xb[i * 4] = o;
    } else {                                             // 72 blocks: W1T / W2T
        int j = (b - NCHUNK - 12500) * 256 + threadIdx.x;
        if (j < 16384) {
            int k = j >> 7, n = j & 127;                 // W1[k][n] -> W1T[n][k]
            W1T[n * 128 + k] = f2bf(W1[j]);
        } else {
            int q = j - 16384;                           // 2048 elements
            int k = q >> 4, n = q & 15;                  // W2[k][n] -> W2T[n][k]
            W2T[n * 128 + k] = f2bf(W2[q]);
        }
    }
}

// Pass D: per-bin fine CSR. LDS histogram over 256 nodes -> dis + absolute cnt starts,
// then LDS returning ranks place col. Replaces scan_blk/scan_top/place.
__global__ __launch_bounds__(256) void passD_kernel(const int* __restrict__ H,
                                                    const int* __restrict__ rec,
                                                    int* __restrict__ col,
                                                    int* __restrict__ cnt,
                                                    float* __restrict__ dis) {
    __shared__ int fh[256];
    __shared__ int s[256];
    __shared__ int run[256];
    int b = blockIdx.x, t = threadIdx.x;
    int estart = H[b * NCHUNK];
    int eend = (b == NBINS - 1) ? N_EDGES : H[(b + 1) * NCHUNK];
    fh[t] = 0;
    __syncthreads();
    for (int e = estart + t; e < eend; e += 256)
        atomicAdd(&fh[rec[e] >> 17], 1);                 // LDS atomic
    __syncthreads();
    int v = fh[t];
    s[t] = v;
    __syncthreads();
    for (int off = 1; off < 256; off <<= 1) {
        int u = (t >= off) ? s[t - off] : 0;
        __syncthreads();
        s[t] += u;
        __syncthreads();
    }
    int node = b * 256 + t;
    int start = estart + s[t] - v;                       // absolute CSR start
    run[t] = start;
    if (node < N_NODES) {
        cnt[node] = start;
        dis[node] = rsqrtf((float)v + 1.0f);
    }
    __syncthreads();
    for (int e = estart + t; e < eend; e += 256) {
        int r = rec[e];
        int p = atomicAdd(&run[r >> 17], 1);             // LDS returning atomic
        col[p] = r & 0x1FFFF;
    }
}

// ---------------- layer-1 aggregation (wave=node, 64 lanes=128 feats, pk-fma) ----------------

__global__ __launch_bounds__(256) void gather1_kernel(const int* __restrict__ col,
                                                      const int* __restrict__ cnt,
                                                      const float* __restrict__ dis,
                                                      const unsigned int* __restrict__ xb,
                                                      unsigned int* __restrict__ xa) {
    int t = threadIdx.x;
    int node = blockIdx.x * 4 + (t >> 6);        // 25000 blocks * 4 = 100000 exact
    int lane = t & 63;
    float dn = dis[node];
    int beg = cnt[node];
    int end = (node == N_NODES - 1) ? N_EDGES : cnt[node + 1];
    unsigned int su = xb[node * 64 + lane];
    f32x2 a0 = bfpair(su) * dn;
    f32x2 a1 = {0.f, 0.f}, a2 = {0.f, 0.f}, a3 = {0.f, 0.f};
    f32x2 a4 = {0.f, 0.f}, a5 = {0.f, 0.f}, a6 = {0.f, 0.f}, a7 = {0.f, 0.f};
    int k = beg;
    for (; k + 8 <= end; k += 8) {
        int s0 = col[k], s1 = col[k + 1], s2 = col[k + 2], s3 = col[k + 3];
        int s4 = col[k + 4], s5 = col[k + 5], s6 = col[k + 6], s7 = col[k + 7];
        float w0 = dis[s0], w1 = dis[s1], w2 = dis[s2], w3 = dis[s3];
        float w4 = dis[s4], w5 = dis[s5], w6 = dis[s6], w7 = dis[s7];
        unsigned int u0 = xb[s0 * 64 + lane], u1 = xb[s1 * 64 + lane];
        unsigned int u2 = xb[s2 * 64 + lane], u3 = xb[s3 * 64 + lane];
        unsigned int u4 = xb[s4 * 64 + lane], u5 = xb[s5 * 64 + lane];
        unsigned int u6 = xb[s6 * 64 + lane], u7 = xb[s7 * 64 + lane];
        a0 += bfpair(u0) * w0;
        a1 += bfpair(u1) * w1;
        a2 += bfpair(u2) * w2;
        a3 += bfpair(u3) * w3;
        a4 += bfpair(u4) * w4;
        a5 += bfpair(u5) * w5;
        a6 += bfpair(u6) * w6;
        a7 += bfpair(u7) * w7;
    }
    for (; k + 4 <= end; k += 4) {
        int s0 = col[k], s1 = col[k + 1], s2 = col[k + 2], s3 = col[k + 3];
        float w0 = dis[s0], w1 = dis[s1], w2 = dis[s2], w3 = dis[s3];
        unsigned int u0 = xb[s0 * 64 + lane], u1 = xb[s1 * 64 + lane];
        unsigned int u2 = xb[s2 * 64 + lane], u3 = xb[s3 * 64 + lane];
        a0 += bfpair(u0) * w0;
        a1 += bfpair(u1) * w1;
        a2 += bfpair(u2) * w2;
        a3 += bfpair(u3) * w3;
    }
    for (; k < end; ++k) {
        int s = col[k];
        float w = dis[s];
        a0 += bfpair(xb[s * 64 + lane]) * w;
    }
    f32x2 r = (((a0 + a1) + (a2 + a3)) + ((a4 + a5) + (a6 + a7))) * dn;
    xa[node * 64 + lane] = (unsigned int)f2bf(r.x) | ((unsigned int)f2bf(r.y) << 16);
}

// ---------------- fused MLP: h2 = relu(xa@W1 + b1) @ W2, h2 emitted as bf16 ----------------

__global__ __launch_bounds__(256) void mlp_kernel(const ushort* __restrict__ xa,
                                                  const ushort* __restrict__ W1T,
                                                  const float* __restrict__ b1,
                                                  const ushort* __restrict__ W2T,
                                                  ushort* __restrict__ h2b) {
    __shared__ ushort sh[4][16][136];   // 136: keeps ds_read_b128 16B-aligned, banks spread
    int t = threadIdx.x;
    int wave = t >> 6, lane = t & 63;
    int l = lane & 15, quad = lane >> 4;
    int m0 = blockIdx.x * 64 + wave * 16;        // 1563*64 = 100032; waves past end idle
    bool valid = (m0 < N_NODES);                 // whole-wave predicate (no early return!)
    int row = valid ? (m0 + l) : 0;

    f32x4 acc[8] = {};
    #pragma unroll
    for (int kk = 0; kk < 4; ++kk) {
        bf16x8 a = *(const bf16x8*)&xa[row * 128 + kk * 32 + quad * 8];
        #pragma unroll
        for (int nt = 0; nt < 8; ++nt) {
            bf16x8 b = *(const bf16x8*)&W1T[(nt * 16 + l) * 128 + kk * 32 + quad * 8];
            acc[nt] = __builtin_amdgcn_mfma_f32_16x16x32_bf16(a, b, acc[nt], 0, 0, 0);
        }
    }
    #pragma unroll
    for (int nt = 0; nt < 8; ++nt) {
        float bias = b1[nt * 16 + l];
        #pragma unroll
        for (int r = 0; r < 4; ++r)
            sh[wave][quad * 4 + r][nt * 16 + l] = f2bf(fmaxf(acc[nt][r] + bias, 0.0f));
    }
    __syncthreads();   // all waves present — orders LDS writes->reads

    f32x4 acc2 = {};
    #pragma unroll
    for (int kk = 0; kk < 4; ++kk) {
        bf16x8 a2 = *(const bf16x8*)&sh[wave][l][kk * 32 + quad * 8];
        bf16x8 bw = *(const bf16x8*)&W2T[l * 128 + kk * 32 + quad * 8];
        acc2 = __builtin_amdgcn_mfma_f32_16x16x32_bf16(a2, bw, acc2, 0, 0, 0);
    }
    if (valid) {
        #pragma unroll
        for (int r = 0; r < 4; ++r)
            h2b[(m0 + quad * 4 + r) * 16 + l] = f2bf(acc2[r]);   // h2[m][n=l]
    }
}

// ---------------- layer-2 gather + bias + log-softmax (bf16 h2, 8 lanes/node, pk-fma) ----------------

__global__ __launch_bounds__(256) void gather2_lsm_kernel(const int* __restrict__ col,
                                                          const int* __restrict__ cnt,
                                                          const float* __restrict__ dis,
                                                          const unsigned int* __restrict__ h2p,
                                                          const float* __restrict__ b2,
                                                          float* __restrict__ out) {
    int t = threadIdx.x;
    int node = blockIdx.x * 32 + (t >> 3);       // 3125 * 32 = 100000 exact
    int c = t & 7;                               // class pair: (2c, 2c+1)
    float dn = dis[node];
    int beg = cnt[node];
    int end = (node == N_NODES - 1) ? N_EDGES : cnt[node + 1];
    unsigned int su = h2p[node * 8 + c];
    f32x2 a0 = bfpair(su) * dn;                  // self-loop term
    f32x2 a1 = {0.f, 0.f}, a2 = {0.f, 0.f}, a3 = {0.f, 0.f};
    f32x2 a4 = {0.f, 0.f}, a5 = {0.f, 0.f}, a6 = {0.f, 0.f}, a7 = {0.f, 0.f};
    int k = beg;
    for (; k + 8 <= end; k += 8) {
        int s0 = col[k], s1 = col[k + 1], s2 = col[k + 2], s3 = col[k + 3];
        int s4 = col[k + 4], s5 = col[k + 5], s6 = col[k + 6], s7 = col[k + 7];
        float w0 = dis[s0], w1 = dis[s1], w2 = dis[s2], w3 = dis[s3];
        float w4 = dis[s4], w5 = dis[s5], w6 = dis[s6], w7 = dis[s7];
        unsigned int u0 = h2p[s0 * 8 + c], u1 = h2p[s1 * 8 + c];
        unsigned int u2 = h2p[s2 * 8 + c], u3 = h2p[s3 * 8 + c];
        unsigned int u4 = h2p[s4 * 8 + c], u5 = h2p[s5 * 8 + c];
        unsigned int u6 = h2p[s6 * 8 + c], u7 = h2p[s7 * 8 + c];
        a0 += bfpair(u0) * w0;
        a1 += bfpair(u1) * w1;
        a2 += bfpair(u2) * w2;
        a3 += bfpair(u3) * w3;
        a4 += bfpair(u4) * w4;
        a5 += bfpair(u5) * w5;
        a6 += bfpair(u6) * w6;
        a7 += bfpair(u7) * w7;
    }
    for (; k + 4 <= end; k += 4) {
        int s0 = col[k], s1 = col[k + 1], s2 = col[k + 2], s3 = col[k + 3];
        float w0 = dis[s0], w1 = dis[s1], w2 = dis[s2], w3 = dis[s3];
        unsigned int u0 = h2p[s0 * 8 + c], u1 = h2p[s1 * 8 + c];
        unsigned int u2 = h2p[s2 * 8 + c], u3 = h2p[s3 * 8 + c];
        a0 += bfpair(u0) * w0;
        a1 += bfpair(u1) * w1;
        a2 += bfpair(u2) * w2;
        a3 += bfpair(u3) * w3;
    }
    for (; k < end; ++k) {
        int s = col[k];
        float w = dis[s];
        a0 += bfpair(h2p[s * 8 + c]) * w;
    }
    f32x2 r = ((a0 + a1) + (a2 + a3)) + ((a4 + a5) + (a6 + a7));
    float2 bb = ((const float2*)b2)[c];
    float v0 = r.x * dn + bb.x;
    float v1 = r.y * dn + bb.y;
    float m = fmaxf(v0, v1);
    #pragma unroll
    for (int off = 1; off < 8; off <<= 1) m = fmaxf(m, __shfl_xor(m, off, 8));
    float ssum = expf(v0 - m) + expf(v1 - m);
    #pragma unroll
    for (int off = 1; off < 8; off <<= 1) ssum += __shfl_xor(ssum, off, 8);
    float lg = m + logf(ssum);
    ((float2*)out)[node * 8 + c] = make_float2(v0 - lg, v1 - lg);
}

// ---------------- launch ----------------

extern "C" void kernel_launch(void* const* d_in, const int* in_sizes, int n_in,
                              void* d_out, int out_size, void* d_ws, size_t ws_size,
                              hipStream_t stream) {
    const float* x  = (const float*)d_in[0];
    const int*   ei = (const int*)d_in[1];
    const float* W1 = (const float*)d_in[2];
    const float* b1 = (const float*)d_in[3];
    const float* W2 = (const float*)d_in[4];
    const float* b2 = (const float*)d_in[5];
    float* out = (float*)d_out;

    const int* src = ei;              // edge_index[0]
    const int* dst = ei + N_EDGES;    // edge_index[1]

    // workspace (bytes), TOTAL = 58,440,960 (unchanged, proven safe R2-R12).
    // xa's region (25.6-51.2 MB) time-shares rec (25.6-32.0) + H (32.0-32.63) during
    // CSR build; both dead before gather1 writes xa. h2b shares xb's region.
    char* ws = (char*)d_ws;
    ushort* xb  = (ushort*)(ws + 0);            // 25,600,000 (node-major bf16)
    ushort* h2b = (ushort*)(ws + 0);            //  3,200,000
    ushort* xa  = (ushort*)(ws + 25600000);     // 25,600,000 (node-major bf16)
    int*    rec = (int*)   (ws + 25600000);     //  6,400,000 (coarse-binned records)
    int*    H   = (int*)   (ws + 32000000);     //    625,600 (hist / scanned bases)
    int*    col = (int*)   (ws + 51200000);     //  6,400,000
    float*  dis = (float*) (ws + 57600000);     //    400,000
    int*    cnt = (int*)   (ws + 58000000);     //    400,000 (absolute CSR starts)
    ushort* W1T = (ushort*)(ws + 58404096);     //     32,768
    ushort* W2T = (ushort*)(ws + 58436864);     //      4,096

    passA_kernel      <<<NCHUNK, 256, 0, stream>>>(dst, H);
    passB_kernel      <<<1, 1024, 0, stream>>>(H);
    passC_kernel      <<<NCHUNK + 12500 + 72, 256, 0, stream>>>(src, dst, H, rec,
                                                                x, W1, W2, xb, W1T, W2T);
    passD_kernel      <<<NBINS, 256, 0, stream>>>(H, rec, col, cnt, dis);

    gather1_kernel    <<<N_NODES / 4, 256, 0, stream>>>(col, cnt, dis,
                                                        (const unsigned int*)xb,
                                                        (unsigned int*)xa);
    mlp_kernel        <<<1563, 256, 0, stream>>>(xa, W1T, b1, W2T, h2b);
    gather2_lsm_kernel<<<3125, 256, 0, stream>>>(col, cnt, dis,
                                                 (const unsigned int*)h2b, b2, out);
}

// Round 14
// 271.159 us; speedup vs baseline: 2.1795x; 2.1795x over previous
//
#include <hip/hip_runtime.h>
#include <math.h>

#define N_NODES 100000
#define N_EDGES 1600000
#define NBINS 391        // coarse bins: dst >> 8 (391*256 = 100096 >= 100000)
#define NCHUNK 400       // edge chunks
#define CHUNK 4000       // edges per chunk (400*4000 = 1.6M exact)
#define M_H (NBINS * NCHUNK)   // 156,400 histogram entries
#define NBLK_H 611       // ceil(M_H / 256)

typedef __attribute__((ext_vector_type(8))) short bf16x8;   // MFMA A/B frag (8 bf16)
typedef __attribute__((ext_vector_type(4))) float f32x4;    // MFMA C/D frag
typedef __attribute__((ext_vector_type(2))) float f32x2;    // packed pair -> v_pk_fma_f32

__device__ __forceinline__ unsigned short f2bf(float f) {   // RNE fp32->bf16
    unsigned int u = __float_as_uint(f);
    u += 0x7FFF + ((u >> 16) & 1);
    return (unsigned short)(u >> 16);
}
__device__ __forceinline__ float bf_lo(unsigned int u) { return __uint_as_float(u << 16); }
__device__ __forceinline__ float bf_hi(unsigned int u) { return __uint_as_float(u & 0xFFFF0000u); }
__device__ __forceinline__ f32x2 bfpair(unsigned int u) {
    f32x2 r; r.x = bf_lo(u); r.y = bf_hi(u); return r;
}

// ---------------- CSR build: two-level counting sort, LDS atomics only ----------------

// Pass A: per-chunk LDS histogram over coarse bins -> H[bin][chunk] (plain stores).
__global__ __launch_bounds__(256) void passA_kernel(const int* __restrict__ dst,
                                                    int* __restrict__ H) {
    __shared__ int lh[NBINS];
    int tid = threadIdx.x, c = blockIdx.x;
    for (int i = tid; i < NBINS; i += 256) lh[i] = 0;
    __syncthreads();
    int base = c * CHUNK;
    #pragma unroll
    for (int i = 0; i < 16; ++i) {
        int o = i * 256 + tid;
        if (o < CHUNK) atomicAdd(&lh[dst[base + o] >> 8], 1);   // LDS atomic
    }
    __syncthreads();
    for (int i = tid; i < NBINS; i += 256) H[i * NCHUNK + c] = lh[i];
}

// Pass B (parallel, replaces R13's 327us single-block scan):
// scanB1: per-block exclusive scan of H + block totals; scanB2: scan of 611 totals.
// Top-level offset (blk2) folded into consumers (R10 pattern).
__global__ __launch_bounds__(256) void scanB1_kernel(int* __restrict__ H,
                                                     int* __restrict__ blk2) {
    __shared__ int s[256];
    int t = threadIdx.x, i = blockIdx.x * 256 + t;
    int v = (i < M_H) ? H[i] : 0;
    s[t] = v;
    __syncthreads();
    for (int off = 1; off < 256; off <<= 1) {
        int u = (t >= off) ? s[t - off] : 0;
        __syncthreads();
        s[t] += u;
        __syncthreads();
    }
    if (i < M_H) H[i] = s[t] - v;                 // exclusive within block
    if (t == 255) blk2[blockIdx.x] = s[255];
}

__global__ __launch_bounds__(1024) void scanB2_kernel(int* __restrict__ blk2) {
    __shared__ int s[1024];
    int t = threadIdx.x;
    int v = (t < NBLK_H) ? blk2[t] : 0;
    s[t] = v;
    __syncthreads();
    for (int off = 1; off < 1024; off <<= 1) {
        int u = (t >= off) ? s[t - off] : 0;
        __syncthreads();
        s[t] += u;
        __syncthreads();
    }
    if (t < NBLK_H) blk2[t] = s[t] - v;
}

// Pass C (merged): coarse scatter (blocks 0..399, LDS returning ranks -> rec) +
// x->bf16 convert (400..12899) + W1T/W2T converts (12900..12971).
// rec[pos] = src | (dst&255)<<17  (25 bits). H base = H[idx] + blk2[idx>>8].
__global__ __launch_bounds__(256) void passC_kernel(const int* __restrict__ src,
                                                    const int* __restrict__ dst,
                                                    const int* __restrict__ H,
                                                    const int* __restrict__ blk2,
                                                    int* __restrict__ rec,
                                                    const float* __restrict__ x,
                                                    const float* __restrict__ W1,
                                                    const float* __restrict__ W2,
                                                    ushort* __restrict__ xb,
                                                    ushort* __restrict__ W1T,
                                                    ushort* __restrict__ W2T) {
    int b = blockIdx.x;
    if (b < NCHUNK) {
        __shared__ int base[NBINS];
        __shared__ int rk[NBINS];
        int tid = threadIdx.x;
        for (int i = tid; i < NBINS; i += 256) {
            int idx = i * NCHUNK + b;
            base[i] = H[idx] + blk2[idx >> 8];
            rk[i] = 0;
        }
        __syncthreads();
        int estart = b * CHUNK;
        #pragma unroll
        for (int i = 0; i < 16; ++i) {
            int o = i * 256 + tid;
            if (o < CHUNK) {
                int e = estart + o;
                int d = dst[e];
                int bin = d >> 8;
                int r = atomicAdd(&rk[bin], 1);          // LDS returning atomic (fast)
                rec[base[bin] + r] = src[e] | ((d & 255) << 17);
            }
        }
    } else if (b < NCHUNK + 12500) {                     // x -> bf16 (node-major)
        int i = (b - NCHUNK) * 256 + threadIdx.x;
        float4 v = *(const float4*)&x[i * 4];
        ushort4 o;
        o.x = f2bf(v.x); o.y = f2bf(v.y); o.z = f2bf(v.z); o.w = f2bf(v.w);
        *(ushort4*)&xb[i * 4] = o;
    } else {                                             // 72 blocks: W1T / W2T
        int j = (b - NCHUNK - 12500) * 256 + threadIdx.x;
        if (j < 16384) {
            int k = j >> 7, n = j & 127;                 // W1[k][n] -> W1T[n][k]
            W1T[n * 128 + k] = f2bf(W1[j]);
        } else {
            int q = j - 16384;                           // 2048 elements
            int k = q >> 4, n = q & 15;                  // W2[k][n] -> W2T[n][k]
            W2T[n * 128 + k] = f2bf(W2[q]);
        }
    }
}

// Pass D: per-bin fine CSR. LDS histogram over 256 nodes -> dis + absolute cnt starts,
// then LDS returning ranks place col.
__global__ __launch_bounds__(256) void passD_kernel(const int* __restrict__ H,
                                                    const int* __restrict__ blk2,
                                                    const int* __restrict__ rec,
                                                    int* __restrict__ col,
                                                    int* __restrict__ cnt,
                                                    float* __restrict__ dis) {
    __shared__ int fh[256];
    __shared__ int s[256];
    __shared__ int run[256];
    int b = blockIdx.x, t = threadIdx.x;
    int i0 = b * NCHUNK;
    int estart = H[i0] + blk2[i0 >> 8];
    int eend;
    if (b == NBINS - 1) eend = N_EDGES;
    else { int i1 = (b + 1) * NCHUNK; eend = H[i1] + blk2[i1 >> 8]; }
    fh[t] = 0;
    __syncthreads();
    for (int e = estart + t; e < eend; e += 256)
        atomicAdd(&fh[rec[e] >> 17], 1);                 // LDS atomic
    __syncthreads();
    int v = fh[t];
    s[t] = v;
    __syncthreads();
    for (int off = 1; off < 256; off <<= 1) {
        int u = (t >= off) ? s[t - off] : 0;
        __syncthreads();
        s[t] += u;
        __syncthreads();
    }
    int node = b * 256 + t;
    int start = estart + s[t] - v;                       // absolute CSR start
    run[t] = start;
    if (node < N_NODES) {
        cnt[node] = start;
        dis[node] = rsqrtf((float)v + 1.0f);
    }
    __syncthreads();
    for (int e = estart + t; e < eend; e += 256) {
        int r = rec[e];
        int p = atomicAdd(&run[r >> 17], 1);             // LDS returning atomic
        col[p] = r & 0x1FFFF;
    }
}

// ---------------- layer-1 aggregation (wave=node, 64 lanes=128 feats, pk-fma) ----------------

__global__ __launch_bounds__(256) void gather1_kernel(const int* __restrict__ col,
                                                      const int* __restrict__ cnt,
                                                      const float* __restrict__ dis,
                                                      const unsigned int* __restrict__ xb,
                                                      unsigned int* __restrict__ xa) {
    int t = threadIdx.x;
    int node = blockIdx.x * 4 + (t >> 6);        // 25000 blocks * 4 = 100000 exact
    int lane = t & 63;
    float dn = dis[node];
    int beg = cnt[node];
    int end = (node == N_NODES - 1) ? N_EDGES : cnt[node + 1];
    unsigned int su = xb[node * 64 + lane];
    f32x2 a0 = bfpair(su) * dn;
    f32x2 a1 = {0.f, 0.f}, a2 = {0.f, 0.f}, a3 = {0.f, 0.f};
    f32x2 a4 = {0.f, 0.f}, a5 = {0.f, 0.f}, a6 = {0.f, 0.f}, a7 = {0.f, 0.f};
    int k = beg;
    for (; k + 8 <= end; k += 8) {
        int s0 = col[k], s1 = col[k + 1], s2 = col[k + 2], s3 = col[k + 3];
        int s4 = col[k + 4], s5 = col[k + 5], s6 = col[k + 6], s7 = col[k + 7];
        float w0 = dis[s0], w1 = dis[s1], w2 = dis[s2], w3 = dis[s3];
        float w4 = dis[s4], w5 = dis[s5], w6 = dis[s6], w7 = dis[s7];
        unsigned int u0 = xb[s0 * 64 + lane], u1 = xb[s1 * 64 + lane];
        unsigned int u2 = xb[s2 * 64 + lane], u3 = xb[s3 * 64 + lane];
        unsigned int u4 = xb[s4 * 64 + lane], u5 = xb[s5 * 64 + lane];
        unsigned int u6 = xb[s6 * 64 + lane], u7 = xb[s7 * 64 + lane];
        a0 += bfpair(u0) * w0;
        a1 += bfpair(u1) * w1;
        a2 += bfpair(u2) * w2;
        a3 += bfpair(u3) * w3;
        a4 += bfpair(u4) * w4;
        a5 += bfpair(u5) * w5;
        a6 += bfpair(u6) * w6;
        a7 += bfpair(u7) * w7;
    }
    for (; k + 4 <= end; k += 4) {
        int s0 = col[k], s1 = col[k + 1], s2 = col[k + 2], s3 = col[k + 3];
        float w0 = dis[s0], w1 = dis[s1], w2 = dis[s2], w3 = dis[s3];
        unsigned int u0 = xb[s0 * 64 + lane], u1 = xb[s1 * 64 + lane];
        unsigned int u2 = xb[s2 * 64 + lane], u3 = xb[s3 * 64 + lane];
        a0 += bfpair(u0) * w0;
        a1 += bfpair(u1) * w1;
        a2 += bfpair(u2) * w2;
        a3 += bfpair(u3) * w3;
    }
    for (; k < end; ++k) {
        int s = col[k];
        float w = dis[s];
        a0 += bfpair(xb[s * 64 + lane]) * w;
    }
    f32x2 r = (((a0 + a1) + (a2 + a3)) + ((a4 + a5) + (a6 + a7))) * dn;
    xa[node * 64 + lane] = (unsigned int)f2bf(r.x) | ((unsigned int)f2bf(r.y) << 16);
}

// ---------------- fused MLP: h2 = relu(xa@W1 + b1) @ W2, h2 emitted as bf16 ----------------

__global__ __launch_bounds__(256) void mlp_kernel(const ushort* __restrict__ xa,
                                                  const ushort* __restrict__ W1T,
                                                  const float* __restrict__ b1,
                                                  const ushort* __restrict__ W2T,
                                                  ushort* __restrict__ h2b) {
    __shared__ ushort sh[4][16][136];   // 136: keeps ds_read_b128 16B-aligned, banks spread
    int t = threadIdx.x;
    int wave = t >> 6, lane = t & 63;
    int l = lane & 15, quad = lane >> 4;
    int m0 = blockIdx.x * 64 + wave * 16;        // 1563*64 = 100032; waves past end idle
    bool valid = (m0 < N_NODES);                 // whole-wave predicate (no early return!)
    int row = valid ? (m0 + l) : 0;

    f32x4 acc[8] = {};
    #pragma unroll
    for (int kk = 0; kk < 4; ++kk) {
        bf16x8 a = *(const bf16x8*)&xa[row * 128 + kk * 32 + quad * 8];
        #pragma unroll
        for (int nt = 0; nt < 8; ++nt) {
            bf16x8 b = *(const bf16x8*)&W1T[(nt * 16 + l) * 128 + kk * 32 + quad * 8];
            acc[nt] = __builtin_amdgcn_mfma_f32_16x16x32_bf16(a, b, acc[nt], 0, 0, 0);
        }
    }
    #pragma unroll
    for (int nt = 0; nt < 8; ++nt) {
        float bias = b1[nt * 16 + l];
        #pragma unroll
        for (int r = 0; r < 4; ++r)
            sh[wave][quad * 4 + r][nt * 16 + l] = f2bf(fmaxf(acc[nt][r] + bias, 0.0f));
    }
    __syncthreads();   // all waves present — orders LDS writes->reads

    f32x4 acc2 = {};
    #pragma unroll
    for (int kk = 0; kk < 4; ++kk) {
        bf16x8 a2 = *(const bf16x8*)&sh[wave][l][kk * 32 + quad * 8];
        bf16x8 bw = *(const bf16x8*)&W2T[l * 128 + kk * 32 + quad * 8];
        acc2 = __builtin_amdgcn_mfma_f32_16x16x32_bf16(a2, bw, acc2, 0, 0, 0);
    }
    if (valid) {
        #pragma unroll
        for (int r = 0; r < 4; ++r)
            h2b[(m0 + quad * 4 + r) * 16 + l] = f2bf(acc2[r]);   // h2[m][n=l]
    }
}

// ---------------- layer-2 gather + bias + log-softmax (bf16 h2, 8 lanes/node, pk-fma) ----------------

__global__ __launch_bounds__(256) void gather2_lsm_kernel(const int* __restrict__ col,
                                                          const int* __restrict__ cnt,
                                                          const float* __restrict__ dis,
                                                          const unsigned int* __restrict__ h2p,
                                                          const float* __restrict__ b2,
                                                          float* __restrict__ out) {
    int t = threadIdx.x;
    int node = blockIdx.x * 32 + (t >> 3);       // 3125 * 32 = 100000 exact
    int c = t & 7;                               // class pair: (2c, 2c+1)
    float dn = dis[node];
    int beg = cnt[node];
    int end = (node == N_NODES - 1) ? N_EDGES : cnt[node + 1];
    unsigned int su = h2p[node * 8 + c];
    f32x2 a0 = bfpair(su) * dn;                  // self-loop term
    f32x2 a1 = {0.f, 0.f}, a2 = {0.f, 0.f}, a3 = {0.f, 0.f};
    f32x2 a4 = {0.f, 0.f}, a5 = {0.f, 0.f}, a6 = {0.f, 0.f}, a7 = {0.f, 0.f};
    int k = beg;
    for (; k + 8 <= end; k += 8) {
        int s0 = col[k], s1 = col[k + 1], s2 = col[k + 2], s3 = col[k + 3];
        int s4 = col[k + 4], s5 = col[k + 5], s6 = col[k + 6], s7 = col[k + 7];
        float w0 = dis[s0], w1 = dis[s1], w2 = dis[s2], w3 = dis[s3];
        float w4 = dis[s4], w5 = dis[s5], w6 = dis[s6], w7 = dis[s7];
        unsigned int u0 = h2p[s0 * 8 + c], u1 = h2p[s1 * 8 + c];
        unsigned int u2 = h2p[s2 * 8 + c], u3 = h2p[s3 * 8 + c];
        unsigned int u4 = h2p[s4 * 8 + c], u5 = h2p[s5 * 8 + c];
        unsigned int u6 = h2p[s6 * 8 + c], u7 = h2p[s7 * 8 + c];
        a0 += bfpair(u0) * w0;
        a1 += bfpair(u1) * w1;
        a2 += bfpair(u2) * w2;
        a3 += bfpair(u3) * w3;
        a4 += bfpair(u4) * w4;
        a5 += bfpair(u5) * w5;
        a6 += bfpair(u6) * w6;
        a7 += bfpair(u7) * w7;
    }
    for (; k + 4 <= end; k += 4) {
        int s0 = col[k], s1 = col[k + 1], s2 = col[k + 2], s3 = col[k + 3];
        float w0 = dis[s0], w1 = dis[s1], w2 = dis[s2], w3 = dis[s3];
        unsigned int u0 = h2p[s0 * 8 + c], u1 = h2p[s1 * 8 + c];
        unsigned int u2 = h2p[s2 * 8 + c], u3 = h2p[s3 * 8 + c];
        a0 += bfpair(u0) * w0;
        a1 += bfpair(u1) * w1;
        a2 += bfpair(u2) * w2;
        a3 += bfpair(u3) * w3;
    }
    for (; k < end; ++k) {
        int s = col[k];
        float w = dis[s];
        a0 += bfpair(h2p[s * 8 + c]) * w;
    }
    f32x2 r = ((a0 + a1) + (a2 + a3)) + ((a4 + a5) + (a6 + a7));
    float2 bb = ((const float2*)b2)[c];
    float v0 = r.x * dn + bb.x;
    float v1 = r.y * dn + bb.y;
    float m = fmaxf(v0, v1);
    #pragma unroll
    for (int off = 1; off < 8; off <<= 1) m = fmaxf(m, __shfl_xor(m, off, 8));
    float ssum = expf(v0 - m) + expf(v1 - m);
    #pragma unroll
    for (int off = 1; off < 8; off <<= 1) ssum += __shfl_xor(ssum, off, 8);
    float lg = m + logf(ssum);
    ((float2*)out)[node * 8 + c] = make_float2(v0 - lg, v1 - lg);
}

// ---------------- launch ----------------

extern "C" void kernel_launch(void* const* d_in, const int* in_sizes, int n_in,
                              void* d_out, int out_size, void* d_ws, size_t ws_size,
                              hipStream_t stream) {
    const float* x  = (const float*)d_in[0];
    const int*   ei = (const int*)d_in[1];
    const float* W1 = (const float*)d_in[2];
    const float* b1 = (const float*)d_in[3];
    const float* W2 = (const float*)d_in[4];
    const float* b2 = (const float*)d_in[5];
    float* out = (float*)d_out;

    const int* src = ei;              // edge_index[0]
    const int* dst = ei + N_EDGES;    // edge_index[1]

    // workspace (bytes), TOTAL = 58,440,960 (unchanged, proven safe R2-R13).
    // xa's region (25.6-51.2 MB) time-shares rec (25.6-32.0) + H (32.0-32.63) during
    // CSR build; both dead before gather1 writes xa. h2b shares xb's region.
    char* ws = (char*)d_ws;
    ushort* xb   = (ushort*)(ws + 0);            // 25,600,000 (node-major bf16)
    ushort* h2b  = (ushort*)(ws + 0);            //  3,200,000
    ushort* xa   = (ushort*)(ws + 25600000);     // 25,600,000 (node-major bf16)
    int*    rec  = (int*)   (ws + 25600000);     //  6,400,000 (coarse-binned records)
    int*    H    = (int*)   (ws + 32000000);     //    625,600 (hist / scanned bases)
    int*    col  = (int*)   (ws + 51200000);     //  6,400,000
    float*  dis  = (float*) (ws + 57600000);     //    400,000
    int*    cnt  = (int*)   (ws + 58000000);     //    400,000 (absolute CSR starts)
    int*    blk2 = (int*)   (ws + 58400000);     //      2,444 (611 scan partials)
    ushort* W1T  = (ushort*)(ws + 58404096);     //     32,768
    ushort* W2T  = (ushort*)(ws + 58436864);     //      4,096

    passA_kernel      <<<NCHUNK, 256, 0, stream>>>(dst, H);
    scanB1_kernel     <<<NBLK_H, 256, 0, stream>>>(H, blk2);
    scanB2_kernel     <<<1, 1024, 0, stream>>>(blk2);
    passC_kernel      <<<NCHUNK + 12500 + 72, 256, 0, stream>>>(src, dst, H, blk2, rec,
                                                                x, W1, W2, xb, W1T, W2T);
    passD_kernel      <<<NBINS, 256, 0, stream>>>(H, blk2, rec, col, cnt, dis);

    gather1_kernel    <<<N_NODES / 4, 256, 0, stream>>>(col, cnt, dis,
                                                        (const unsigned int*)xb,
                                                        (unsigned int*)xa);
    mlp_kernel        <<<1563, 256, 0, stream>>>(xa, W1T, b1, W2T, h2b);
    gather2_lsm_kernel<<<3125, 256, 0, stream>>>(col, cnt, dis,
                                                 (const unsigned int*)h2b, b2, out);
}